// Round 3
// baseline (235.721 us; speedup 1.0000x reference)
//
#include <hip/hip_runtime.h>
#include <cstdint>

#define E_CNT 131072
#define N_CNT 4096

typedef short bf16x8 __attribute__((ext_vector_type(8)));
typedef float f32x4 __attribute__((ext_vector_type(4)));

__device__ __forceinline__ ushort f2bf(float f) {
  union { float f; unsigned u; } v; v.f = f;
  unsigned r = v.u + 0x7FFFu + ((v.u >> 16) & 1u);
  return (ushort)(r >> 16);
}

// ---------------- tiny zero for deg ----------------
__global__ __launch_bounds__(256) void k_zero_deg(int* __restrict__ p) {
  p[blockIdx.x * 256 + threadIdx.x] = 0;
}

// ---------------- fused prep: cvt_x | deg-hist | wtmp | c1-zero -----------
__global__ __launch_bounds__(256) void k_prep(const float4* __restrict__ x,
                                              ushort* __restrict__ xbf,
                                              const int* __restrict__ dstp,
                                              int* __restrict__ deg,
                                              const float* __restrict__ att1,
                                              const float* __restrict__ basis1,
                                              float* __restrict__ wtmp,
                                              int* __restrict__ c1i) {
  int bid = blockIdx.x, tid = threadIdx.x;
  if (bid < 16384) {
    int i = bid * 256 + tid;
    float4 v = x[i];
    ushort4 o;
    o.x = f2bf(v.x); o.y = f2bf(v.y); o.z = f2bf(v.z); o.w = f2bf(v.w);
    *(ushort4*)(xbf + (size_t)i * 4) = o;
  } else if (bid < 16896) {
    int e = (bid - 16384) * 256 + tid;
    atomicAdd(&deg[dstp[e]], 1);
  } else if (bid < 17920) {
    int flat = (bid - 16896) * 256 + tid;  // i*64+o
    float a[8] = {0.f, 0.f, 0.f, 0.f, 0.f, 0.f, 0.f, 0.f};
    for (int b = 0; b < 30; ++b) {
      float v = basis1[(size_t)b * 262144 + flat];
#pragma unroll
      for (int r = 0; r < 8; ++r) a[r] += att1[r * 30 + b] * v;
    }
#pragma unroll
    for (int r = 0; r < 8; ++r) wtmp[(size_t)r * 262144 + flat] = a[r];
  } else {
    int flat = (bid - 17920) * 256 + tid;  // < 2359296 = 4096*576
    c1i[flat] = 0;
  }
}

// ---------------- exclusive scan over 4096 degrees (1 block) --------------
__global__ __launch_bounds__(1024) void k_scan(const int* __restrict__ deg,
                                               int* __restrict__ rowptr,
                                               int* __restrict__ cursor,
                                               float* __restrict__ dinv) {
  __shared__ int part[1024];
  int t = threadIdx.x;
  int base = t * 4;
  int d0 = deg[base], d1 = deg[base + 1], d2 = deg[base + 2], d3 = deg[base + 3];
  int s = d0 + d1 + d2 + d3;
  part[t] = s;
  __syncthreads();
  for (int off = 1; off < 1024; off <<= 1) {
    int v = part[t];
    int u = (t >= off) ? part[t - off] : 0;
    __syncthreads();
    part[t] = v + u;
    __syncthreads();
  }
  int incl = part[t];
  int excl = incl - s;
  int p0 = excl, p1 = excl + d0, p2 = p1 + d1, p3 = p2 + d2;
  rowptr[base] = p0; rowptr[base + 1] = p1; rowptr[base + 2] = p2; rowptr[base + 3] = p3;
  cursor[base] = p0; cursor[base + 1] = p1; cursor[base + 2] = p2; cursor[base + 3] = p3;
  dinv[base]     = 1.0f / fmaxf((float)d0, 1.0f);
  dinv[base + 1] = 1.0f / fmaxf((float)d1, 1.0f);
  dinv[base + 2] = 1.0f / fmaxf((float)d2, 1.0f);
  dinv[base + 3] = 1.0f / fmaxf((float)d3, 1.0f);
  if (t == 1023) rowptr[4096] = incl;
}

// ---------------- fused mid: CSR-fill | transpose W1 | W2 combine ---------
__global__ __launch_bounds__(256) void k_mid(const int* __restrict__ srcp,
                                             const int* __restrict__ dstp,
                                             const int* __restrict__ et,
                                             int* __restrict__ cursor,
                                             int* __restrict__ spack,
                                             const float* __restrict__ wtmp,
                                             const float* __restrict__ root1,
                                             ushort* __restrict__ wt1,
                                             const float* __restrict__ att2,
                                             const float* __restrict__ basis2,
                                             const float* __restrict__ root2,
                                             float* __restrict__ w2e) {
  __shared__ float tile[64 * 65];
  int bid = blockIdx.x, t = threadIdx.x;
  if (bid < 512) {
    int e = bid * 256 + t;
    int d = dstp[e];
    int pos = atomicAdd(&cursor[d], 1);
    spack[pos] = (srcp[e] << 3) | et[e];
  } else if (bid < 1088) {
    int bb = bid - 512;
    int r = bb >> 6;                // 0..8
    int i0 = (bb & 63) * 64;
    const float* sp = (r < 8) ? (wtmp + (size_t)r * 262144) : root1;
#pragma unroll
    for (int it = 0; it < 16; ++it) {
      int flat = it * 256 + t;
      int il = flat >> 6, o = flat & 63;
      tile[il * 65 + o] = sp[(size_t)(i0 + il) * 64 + o];
    }
    __syncthreads();
#pragma unroll
    for (int it = 0; it < 16; ++it) {
      int flat = it * 256 + t;
      int o = flat >> 6, il = flat & 63;
      wt1[(size_t)(r * 64 + o) * 4096 + i0 + il] = f2bf(tile[il * 65 + o]);
    }
  } else {
    int r = bid - 1088;  // 0..8
    for (int q = t; q < 1024; q += 256) {
      float a = 0.f;
      if (r < 8) {
        for (int b = 0; b < 30; ++b) a += att2[r * 30 + b] * basis2[b * 1024 + q];
      } else {
        a = root2[q];
      }
      w2e[r * 1024 + q] = a;
    }
  }
}

// ---------------- split-K GEMM, register-direct (no LDS, no barriers) -----
// c1[4096][576] += xbf @ wt1^T.  BM=128 BN=64 BK=64, SPLITK=4, 256 thr =
// 4 independent waves (2x2), wave tile 64x32. A/B fragments loaded straight
// from global in MFMA layout; latency hidden by unroll + 12 waves/CU.
__global__ __launch_bounds__(256) void k_gemm1(const ushort* __restrict__ xbf,
                                               const ushort* __restrict__ wt1,
                                               float* __restrict__ c1) {
  int bid = blockIdx.x;
  int swz = (bid & 7) * 144 + (bid >> 3);  // 1152 = 8*144, bijective
  int kp = swz / 288, t2 = swz % 288;
  int bm = t2 / 9, bn = t2 % 9;
  int m0 = bm * 128, n0 = bn * 64, kbase = kp * 1024;
  int lane = threadIdx.x & 63, wid = threadIdx.x >> 6;
  int wm = wid >> 1, wn = wid & 1;
  int r16 = lane & 15, q8 = (lane >> 4) * 8;

  const ushort* Ab = xbf + (size_t)(m0 + wm * 64 + r16) * 4096 + kbase + q8;
  const ushort* Bb = wt1 + (size_t)(n0 + wn * 32 + r16) * 4096 + kbase + q8;

  f32x4 acc[4][2] = {};

#pragma unroll 4
  for (int t = 0; t < 16; ++t) {
    int ko = t * 64;
    bf16x8 a[2][4], b[2][2];
#pragma unroll
    for (int ks = 0; ks < 2; ++ks) {
#pragma unroll
      for (int mi = 0; mi < 4; ++mi)
        a[ks][mi] = *(const bf16x8*)(Ab + (size_t)mi * 16 * 4096 + ko + ks * 32);
#pragma unroll
      for (int ni = 0; ni < 2; ++ni)
        b[ks][ni] = *(const bf16x8*)(Bb + (size_t)ni * 16 * 4096 + ko + ks * 32);
    }
#pragma unroll
    for (int ks = 0; ks < 2; ++ks)
#pragma unroll
      for (int mi = 0; mi < 4; ++mi)
#pragma unroll
        for (int ni = 0; ni < 2; ++ni)
          acc[mi][ni] = __builtin_amdgcn_mfma_f32_16x16x32_bf16(a[ks][mi], b[ks][ni], acc[mi][ni], 0, 0, 0);
  }

  int cf = lane & 15, rf4 = (lane >> 4) * 4;
#pragma unroll
  for (int mi = 0; mi < 4; ++mi)
#pragma unroll
    for (int ni = 0; ni < 2; ++ni) {
      int gcol = n0 + wn * 32 + ni * 16 + cf;
#pragma unroll
      for (int j = 0; j < 4; ++j) {
        int grow = m0 + wm * 64 + mi * 16 + rf4 + j;
        atomicAdd(&c1[(size_t)grow * 576 + gcol], acc[mi][ni][j]);
      }
    }
}

// ---------------- fused layer-1 aggregate + relu + layer-2 transform ------
__global__ __launch_bounds__(64) void k_agg1h2(const float* __restrict__ c1,
                                               const int* __restrict__ rowptr,
                                               const int* __restrict__ spack,
                                               const float* __restrict__ dinv,
                                               const float* __restrict__ bias1,
                                               const float* __restrict__ w2e,
                                               float* __restrict__ h2c) {
  __shared__ float sh[64];
  int n = blockIdx.x, t = threadIdx.x;  // t = feature h
  int s0 = rowptr[n], s1 = rowptr[n + 1];
  float acc = 0.f;
  int e = s0;
  for (; e + 3 < s1; e += 4) {
    int p0 = spack[e], p1 = spack[e + 1], p2 = spack[e + 2], p3 = spack[e + 3];
    float v0 = c1[(size_t)(p0 >> 3) * 576 + (p0 & 7) * 64 + t];
    float v1 = c1[(size_t)(p1 >> 3) * 576 + (p1 & 7) * 64 + t];
    float v2 = c1[(size_t)(p2 >> 3) * 576 + (p2 & 7) * 64 + t];
    float v3 = c1[(size_t)(p3 >> 3) * 576 + (p3 & 7) * 64 + t];
    acc += (v0 + v1) + (v2 + v3);
  }
  for (; e < s1; ++e) {
    int p = spack[e];
    acc += c1[(size_t)(p >> 3) * 576 + (p & 7) * 64 + t];
  }
  float v = acc * dinv[n] + c1[(size_t)n * 576 + 512 + t] + bias1[t];
  sh[t] = fmaxf(v, 0.f);
  __syncthreads();
  float* o = h2c + (size_t)n * 144;
  for (int rc = t; rc < 144; rc += 64) {
    int r9 = rc >> 4, c = rc & 15;
    const float* w = w2e + r9 * 1024 + c;
    float a = 0.f;
#pragma unroll
    for (int hh = 0; hh < 64; ++hh) a += sh[hh] * w[hh * 16];
    o[rc] = a;
  }
}

// ---------------- layer-2 aggregate + root + bias + log_softmax -----------
__global__ __launch_bounds__(64) void k_agg2(const float* __restrict__ h2c,
                                             const int* __restrict__ rowptr,
                                             const int* __restrict__ spack,
                                             const float* __restrict__ dinv,
                                             const float* __restrict__ bias2,
                                             float* __restrict__ out) {
  __shared__ float red[64];
  int n = blockIdx.x, t = threadIdx.x;
  int c = t & 15, q = t >> 4;
  int s0 = rowptr[n], s1 = rowptr[n + 1];
  float acc = 0.f;
  for (int e = s0 + q; e < s1; e += 4) {
    int p = spack[e];
    acc += h2c[(size_t)(p >> 3) * 144 + (p & 7) * 16 + c];
  }
  red[t] = acc;
  __syncthreads();
  if (t < 16) {
    float sum = red[c] + red[16 + c] + red[32 + c] + red[48 + c];
    float v = sum * dinv[n] + h2c[(size_t)n * 144 + 128 + c] + bias2[c];
    float m = v;
#pragma unroll
    for (int off = 1; off < 16; off <<= 1) m = fmaxf(m, __shfl_xor(m, off, 64));
    float ex = expf(v - m);
    float s = ex;
#pragma unroll
    for (int off = 1; off < 16; off <<= 1) s += __shfl_xor(s, off, 64);
    out[n * 16 + c] = v - m - logf(s);
  }
}

extern "C" void kernel_launch(void* const* d_in, const int* in_sizes, int n_in,
                              void* d_out, int out_size, void* d_ws, size_t ws_size,
                              hipStream_t stream) {
  const float* x      = (const float*)d_in[0];
  const int*   ei     = (const int*)d_in[1];
  const int*   et     = (const int*)d_in[2];
  const float* basis1 = (const float*)d_in[3];
  const float* att1   = (const float*)d_in[4];
  const float* root1  = (const float*)d_in[5];
  const float* bias1  = (const float*)d_in[6];
  const float* basis2 = (const float*)d_in[7];
  const float* att2   = (const float*)d_in[8];
  const float* root2  = (const float*)d_in[9];
  const float* bias2  = (const float*)d_in[10];
  float* out = (float*)d_out;

  char* ws = (char*)d_ws;
  size_t off = 0;
  auto alloc = [&](size_t bytes) {
    void* p = ws + off;
    off = (off + bytes + 255) & ~(size_t)255;
    return p;
  };
  ushort* xbf  = (ushort*)alloc((size_t)N_CNT * N_CNT * 2);
  ushort* wt1  = (ushort*)alloc((size_t)576 * 4096 * 2);
  float*  wtmp = (float*)alloc((size_t)8 * N_CNT * 64 * 4);
  float*  c1   = (float*)alloc((size_t)N_CNT * 576 * 4);
  float*  w2e  = (float*)alloc((size_t)9 * 64 * 16 * 4);
  float*  h2c  = (float*)alloc((size_t)N_CNT * 144 * 4);
  int*    deg    = (int*)alloc(4096 * 4);
  float*  dinv   = (float*)alloc(4096 * 4);
  int*    rowptr = (int*)alloc(4097 * 4);
  int*    cursor = (int*)alloc(4096 * 4);
  int*    spack  = (int*)alloc((size_t)E_CNT * 4);

  const int* srcp = ei;
  const int* dstp = ei + E_CNT;

  k_zero_deg<<<16, 256, 0, stream>>>(deg);
  k_prep<<<27136, 256, 0, stream>>>((const float4*)x, xbf, dstp, deg,
                                    att1, basis1, wtmp, (int*)c1);
  k_scan<<<1, 1024, 0, stream>>>(deg, rowptr, cursor, dinv);
  k_mid<<<1097, 256, 0, stream>>>(srcp, dstp, et, cursor, spack,
                                  wtmp, root1, wt1, att2, basis2, root2, w2e);
  k_gemm1<<<1152, 256, 0, stream>>>(xbf, wt1, c1);
  k_agg1h2<<<4096, 64, 0, stream>>>(c1, rowptr, spack, dinv, bias1, w2e, h2c);
  k_agg2<<<4096, 64, 0, stream>>>(h2c, rowptr, spack, dinv, bias2, out);
}

// Round 4
// 142.013 us; speedup vs baseline: 1.6599x; 1.6599x over previous
//
#include <hip/hip_runtime.h>
#include <cstdint>

#define E_CNT 131072
#define N_CNT 4096

typedef short bf16x8 __attribute__((ext_vector_type(8)));
typedef float f32x4 __attribute__((ext_vector_type(4)));

__device__ __forceinline__ ushort f2bf(float f) {
  union { float f; unsigned u; } v; v.f = f;
  unsigned r = v.u + 0x7FFFu + ((v.u >> 16) & 1u);
  return (ushort)(r >> 16);
}

// ---------------- tiny zero for deg ----------------
__global__ __launch_bounds__(256) void k_zero_deg(int* __restrict__ p) {
  p[blockIdx.x * 256 + threadIdx.x] = 0;
}

// ---------------- fused prep: cvt_x | deg-hist | wtmp | c1-zero -----------
__global__ __launch_bounds__(256) void k_prep(const float4* __restrict__ x,
                                              ushort* __restrict__ xbf,
                                              const int* __restrict__ dstp,
                                              int* __restrict__ deg,
                                              const float* __restrict__ att1,
                                              const float* __restrict__ basis1,
                                              float* __restrict__ wtmp,
                                              int* __restrict__ c1i) {
  int bid = blockIdx.x, tid = threadIdx.x;
  if (bid < 16384) {
    int i = bid * 256 + tid;
    float4 v = x[i];
    ushort4 o;
    o.x = f2bf(v.x); o.y = f2bf(v.y); o.z = f2bf(v.z); o.w = f2bf(v.w);
    *(ushort4*)(xbf + (size_t)i * 4) = o;
  } else if (bid < 16896) {
    int e = (bid - 16384) * 256 + tid;
    atomicAdd(&deg[dstp[e]], 1);
  } else if (bid < 17920) {
    int flat = (bid - 16896) * 256 + tid;  // i*64+o
    float a[8] = {0.f, 0.f, 0.f, 0.f, 0.f, 0.f, 0.f, 0.f};
    for (int b = 0; b < 30; ++b) {
      float v = basis1[(size_t)b * 262144 + flat];
#pragma unroll
      for (int r = 0; r < 8; ++r) a[r] += att1[r * 30 + b] * v;
    }
#pragma unroll
    for (int r = 0; r < 8; ++r) wtmp[(size_t)r * 262144 + flat] = a[r];
  } else {
    int flat = (bid - 17920) * 256 + tid;  // < 2359296 = 4096*576
    c1i[flat] = 0;
  }
}

// ---------------- exclusive scan over 4096 degrees (1 block) --------------
__global__ __launch_bounds__(1024) void k_scan(const int* __restrict__ deg,
                                               int* __restrict__ rowptr,
                                               int* __restrict__ cursor,
                                               float* __restrict__ dinv) {
  __shared__ int part[1024];
  int t = threadIdx.x;
  int base = t * 4;
  int d0 = deg[base], d1 = deg[base + 1], d2 = deg[base + 2], d3 = deg[base + 3];
  int s = d0 + d1 + d2 + d3;
  part[t] = s;
  __syncthreads();
  for (int off = 1; off < 1024; off <<= 1) {
    int v = part[t];
    int u = (t >= off) ? part[t - off] : 0;
    __syncthreads();
    part[t] = v + u;
    __syncthreads();
  }
  int incl = part[t];
  int excl = incl - s;
  int p0 = excl, p1 = excl + d0, p2 = p1 + d1, p3 = p2 + d2;
  rowptr[base] = p0; rowptr[base + 1] = p1; rowptr[base + 2] = p2; rowptr[base + 3] = p3;
  cursor[base] = p0; cursor[base + 1] = p1; cursor[base + 2] = p2; cursor[base + 3] = p3;
  dinv[base]     = 1.0f / fmaxf((float)d0, 1.0f);
  dinv[base + 1] = 1.0f / fmaxf((float)d1, 1.0f);
  dinv[base + 2] = 1.0f / fmaxf((float)d2, 1.0f);
  dinv[base + 3] = 1.0f / fmaxf((float)d3, 1.0f);
  if (t == 1023) rowptr[4096] = incl;
}

// ---------------- fused mid: CSR-fill | transpose W1 | W2 combine ---------
__global__ __launch_bounds__(256) void k_mid(const int* __restrict__ srcp,
                                             const int* __restrict__ dstp,
                                             const int* __restrict__ et,
                                             int* __restrict__ cursor,
                                             int* __restrict__ spack,
                                             const float* __restrict__ wtmp,
                                             const float* __restrict__ root1,
                                             ushort* __restrict__ wt1,
                                             const float* __restrict__ att2,
                                             const float* __restrict__ basis2,
                                             const float* __restrict__ root2,
                                             float* __restrict__ w2e) {
  __shared__ float tile[64 * 65];
  int bid = blockIdx.x, t = threadIdx.x;
  if (bid < 512) {
    int e = bid * 256 + t;
    int d = dstp[e];
    int pos = atomicAdd(&cursor[d], 1);
    spack[pos] = (srcp[e] << 3) | et[e];
  } else if (bid < 1088) {
    int bb = bid - 512;
    int r = bb >> 6;                // 0..8
    int i0 = (bb & 63) * 64;
    const float* sp = (r < 8) ? (wtmp + (size_t)r * 262144) : root1;
#pragma unroll
    for (int it = 0; it < 16; ++it) {
      int flat = it * 256 + t;
      int il = flat >> 6, o = flat & 63;
      tile[il * 65 + o] = sp[(size_t)(i0 + il) * 64 + o];
    }
    __syncthreads();
#pragma unroll
    for (int it = 0; it < 16; ++it) {
      int flat = it * 256 + t;
      int o = flat >> 6, il = flat & 63;
      wt1[(size_t)(r * 64 + o) * 4096 + i0 + il] = f2bf(tile[il * 65 + o]);
    }
  } else {
    int r = bid - 1088;  // 0..8
    for (int q = t; q < 1024; q += 256) {
      float a = 0.f;
      if (r < 8) {
        for (int b = 0; b < 30; ++b) a += att2[r * 30 + b] * basis2[b * 1024 + q];
      } else {
        a = root2[q];
      }
      w2e[r * 1024 + q] = a;
    }
  }
}

// ---------------- split-K GEMM: c1[4096][576] += xbf @ wt1^T --------------
// BM=128 BN=64 BK=64, SPLITK=2 (32 K-steps), 256 thr (2x2 waves, 64x32/wave).
// 3-buffer LDS pipeline, 2-deep prefetch, counted vmcnt(6) (never 0 in loop),
// ONE raw s_barrier per K-step. XOR-chunk swizzle both-sides (rule #21).
#define TSTEPS 32
__global__ __launch_bounds__(256) void k_gemm1(const ushort* __restrict__ xbf,
                                               const ushort* __restrict__ wt1,
                                               float* __restrict__ c1) {
  __shared__ __align__(16) ushort As[3][128 * 64];
  __shared__ __align__(16) ushort Bs[3][64 * 64];
  int bid = blockIdx.x;
  int swz = (bid & 7) * 72 + (bid >> 3);  // 576 = 8*72, bijective XCD swizzle
  int kp = swz / 288, t2 = swz % 288;
  int bm = t2 / 9, bn = t2 % 9;
  int m0 = bm * 128, n0 = bn * 64, kbase = kp * 2048;
  int tid = threadIdx.x;
  int lane = tid & 63, wid = tid >> 6;
  int wm = wid >> 1, wn = wid & 1;

  f32x4 acc[4][2] = {};

  auto stage = [&](int s, int k0) {
#pragma unroll
    for (int it = 0; it < 4; ++it) {
      int flat = it * 256 + tid;
      int row = flat >> 3, gg = flat & 7;
      int gcol = k0 + ((gg ^ (row & 7)) << 3);  // pre-swizzled global source
      const ushort* g = xbf + (size_t)(m0 + row) * 4096 + gcol;
      ushort* l = &As[s][(it * 256 + wid * 64) * 8];  // linear LDS dest
      __builtin_amdgcn_global_load_lds((const __attribute__((address_space(1))) void*)g,
                                       (__attribute__((address_space(3))) void*)l, 16, 0, 0);
    }
#pragma unroll
    for (int it = 0; it < 2; ++it) {
      int flat = it * 256 + tid;
      int row = flat >> 3, gg = flat & 7;
      int gcol = k0 + ((gg ^ (row & 7)) << 3);
      const ushort* g = wt1 + (size_t)(n0 + row) * 4096 + gcol;
      ushort* l = &Bs[s][(it * 256 + wid * 64) * 8];
      __builtin_amdgcn_global_load_lds((const __attribute__((address_space(1))) void*)g,
                                       (__attribute__((address_space(3))) void*)l, 16, 0, 0);
    }
  };

  stage(0, kbase);
  stage(1, kbase + 64);

  int cb = 0;  // buffer holding K-step t
  for (int t = 0; t < TSTEPS; ++t) {
    // wait own stage(t) loads (6 of stage(t+1) may stay in flight), then sync:
    // barrier release => ALL waves' stage(t) landed.
    if (t < TSTEPS - 1) {
      asm volatile("s_waitcnt vmcnt(6)" ::: "memory");
    } else {
      asm volatile("s_waitcnt vmcnt(0)" ::: "memory");
    }
    __builtin_amdgcn_s_barrier();
    if (t + 2 < TSTEPS) {
      int sb = cb == 0 ? 2 : cb - 1;  // (t+2)%3
      stage(sb, kbase + (t + 2) * 64);
    }
    int q = lane >> 4, sw = lane & 7, r16 = lane & 15;
    bf16x8 a[2][4], b[2][2];
#pragma unroll
    for (int ks = 0; ks < 2; ++ks) {
      int co = ((ks * 4 + q) ^ sw) << 3;
#pragma unroll
      for (int ni = 0; ni < 2; ++ni)
        b[ks][ni] = *(const bf16x8*)&Bs[cb][(wn * 32 + ni * 16 + r16) * 64 + co];
#pragma unroll
      for (int mi = 0; mi < 4; ++mi)
        a[ks][mi] = *(const bf16x8*)&As[cb][(wm * 64 + mi * 16 + r16) * 64 + co];
    }
    __builtin_amdgcn_s_setprio(1);
#pragma unroll
    for (int ks = 0; ks < 2; ++ks)
#pragma unroll
      for (int mi = 0; mi < 4; ++mi)
#pragma unroll
        for (int ni = 0; ni < 2; ++ni)
          acc[mi][ni] = __builtin_amdgcn_mfma_f32_16x16x32_bf16(a[ks][mi], b[ks][ni], acc[mi][ni], 0, 0, 0);
    __builtin_amdgcn_s_setprio(0);
    cb = cb == 2 ? 0 : cb + 1;
  }

  int cf = lane & 15, rf4 = (lane >> 4) * 4;
#pragma unroll
  for (int mi = 0; mi < 4; ++mi)
#pragma unroll
    for (int ni = 0; ni < 2; ++ni) {
      int gcol = n0 + wn * 32 + ni * 16 + cf;
#pragma unroll
      for (int j = 0; j < 4; ++j) {
        int grow = m0 + wm * 64 + mi * 16 + rf4 + j;
        atomicAdd(&c1[(size_t)grow * 576 + gcol], acc[mi][ni][j]);
      }
    }
}

// -------- fused layer-1 aggregate + relu + layer-2 transform (4 nodes/blk) -
__global__ __launch_bounds__(256) void k_agg1h2(const float* __restrict__ c1,
                                                const int* __restrict__ rowptr,
                                                const int* __restrict__ spack,
                                                const float* __restrict__ dinv,
                                                const float* __restrict__ bias1,
                                                const float* __restrict__ w2e,
                                                float* __restrict__ h2c) {
  __shared__ float sh[4][64];
  int g = threadIdx.x >> 6, t = threadIdx.x & 63;
  int n = blockIdx.x * 4 + g;
  int s0 = rowptr[n], s1 = rowptr[n + 1];
  float acc = 0.f;
  int e = s0;
  for (; e + 3 < s1; e += 4) {
    int p0 = spack[e], p1 = spack[e + 1], p2 = spack[e + 2], p3 = spack[e + 3];
    float v0 = c1[(size_t)(p0 >> 3) * 576 + (p0 & 7) * 64 + t];
    float v1 = c1[(size_t)(p1 >> 3) * 576 + (p1 & 7) * 64 + t];
    float v2 = c1[(size_t)(p2 >> 3) * 576 + (p2 & 7) * 64 + t];
    float v3 = c1[(size_t)(p3 >> 3) * 576 + (p3 & 7) * 64 + t];
    acc += (v0 + v1) + (v2 + v3);
  }
  for (; e < s1; ++e) {
    int p = spack[e];
    acc += c1[(size_t)(p >> 3) * 576 + (p & 7) * 64 + t];
  }
  float v = acc * dinv[n] + c1[(size_t)n * 576 + 512 + t] + bias1[t];
  sh[g][t] = fmaxf(v, 0.f);
  __syncthreads();
  float* o = h2c + (size_t)n * 144;
  for (int rc = t; rc < 144; rc += 64) {
    int r9 = rc >> 4, c = rc & 15;
    const float* w = w2e + r9 * 1024 + c;
    float a = 0.f;
#pragma unroll
    for (int hh = 0; hh < 64; ++hh) a += sh[g][hh] * w[hh * 16];
    o[rc] = a;
  }
}

// ---------------- layer-2 aggregate + root + bias + log_softmax -----------
__global__ __launch_bounds__(64) void k_agg2(const float* __restrict__ h2c,
                                             const int* __restrict__ rowptr,
                                             const int* __restrict__ spack,
                                             const float* __restrict__ dinv,
                                             const float* __restrict__ bias2,
                                             float* __restrict__ out) {
  __shared__ float red[64];
  int n = blockIdx.x, t = threadIdx.x;
  int c = t & 15, q = t >> 4;
  int s0 = rowptr[n], s1 = rowptr[n + 1];
  float acc = 0.f;
  for (int e = s0 + q; e < s1; e += 4) {
    int p = spack[e];
    acc += h2c[(size_t)(p >> 3) * 144 + (p & 7) * 16 + c];
  }
  red[t] = acc;
  __syncthreads();
  if (t < 16) {
    float sum = red[c] + red[16 + c] + red[32 + c] + red[48 + c];
    float v = sum * dinv[n] + h2c[(size_t)n * 144 + 128 + c] + bias2[c];
    float m = v;
#pragma unroll
    for (int off = 1; off < 16; off <<= 1) m = fmaxf(m, __shfl_xor(m, off, 64));
    float ex = expf(v - m);
    float s = ex;
#pragma unroll
    for (int off = 1; off < 16; off <<= 1) s += __shfl_xor(s, off, 64);
    out[n * 16 + c] = v - m - logf(s);
  }
}

extern "C" void kernel_launch(void* const* d_in, const int* in_sizes, int n_in,
                              void* d_out, int out_size, void* d_ws, size_t ws_size,
                              hipStream_t stream) {
  const float* x      = (const float*)d_in[0];
  const int*   ei     = (const int*)d_in[1];
  const int*   et     = (const int*)d_in[2];
  const float* basis1 = (const float*)d_in[3];
  const float* att1   = (const float*)d_in[4];
  const float* root1  = (const float*)d_in[5];
  const float* bias1  = (const float*)d_in[6];
  const float* basis2 = (const float*)d_in[7];
  const float* att2   = (const float*)d_in[8];
  const float* root2  = (const float*)d_in[9];
  const float* bias2  = (const float*)d_in[10];
  float* out = (float*)d_out;

  char* ws = (char*)d_ws;
  size_t off = 0;
  auto alloc = [&](size_t bytes) {
    void* p = ws + off;
    off = (off + bytes + 255) & ~(size_t)255;
    return p;
  };
  ushort* xbf  = (ushort*)alloc((size_t)N_CNT * N_CNT * 2);
  ushort* wt1  = (ushort*)alloc((size_t)576 * 4096 * 2);
  float*  wtmp = (float*)alloc((size_t)8 * N_CNT * 64 * 4);
  float*  c1   = (float*)alloc((size_t)N_CNT * 576 * 4);
  float*  w2e  = (float*)alloc((size_t)9 * 64 * 16 * 4);
  float*  h2c  = (float*)alloc((size_t)N_CNT * 144 * 4);
  int*    deg    = (int*)alloc(4096 * 4);
  float*  dinv   = (float*)alloc(4096 * 4);
  int*    rowptr = (int*)alloc(4097 * 4);
  int*    cursor = (int*)alloc(4096 * 4);
  int*    spack  = (int*)alloc((size_t)E_CNT * 4);

  const int* srcp = ei;
  const int* dstp = ei + E_CNT;

  k_zero_deg<<<16, 256, 0, stream>>>(deg);
  k_prep<<<27136, 256, 0, stream>>>((const float4*)x, xbf, dstp, deg,
                                    att1, basis1, wtmp, (int*)c1);
  k_scan<<<1, 1024, 0, stream>>>(deg, rowptr, cursor, dinv);
  k_mid<<<1097, 256, 0, stream>>>(srcp, dstp, et, cursor, spack,
                                  wtmp, root1, wt1, att2, basis2, root2, w2e);
  k_gemm1<<<576, 256, 0, stream>>>(xbf, wt1, c1);
  k_agg1h2<<<1024, 256, 0, stream>>>(c1, rowptr, spack, dinv, bias1, w2e, h2c);
  k_agg2<<<4096, 64, 0, stream>>>(h2c, rowptr, spack, dinv, bias2, out);
}

// Round 5
// 131.415 us; speedup vs baseline: 1.7937x; 1.0806x over previous
//
#include <hip/hip_runtime.h>
#include <cstdint>

#define E_CNT 131072
#define N_CNT 4096

typedef short bf16x8 __attribute__((ext_vector_type(8)));
typedef float f32x4 __attribute__((ext_vector_type(4)));

__device__ __forceinline__ ushort f2bf(float f) {
  union { float f; unsigned u; } v; v.f = f;
  unsigned r = v.u + 0x7FFFu + ((v.u >> 16) & 1u);
  return (ushort)(r >> 16);
}

// ---- fused prep: cvt_x | deg-hist | W1 combine+transpose | c1-zero -------
// blocks [0,16384): x fp32->bf16
// [16384,16896): degree histogram
// [16896,17152): wt1[r*64+o][i] = f2bf(sum_b att1[r,b]*basis1[b,i,o]), r<8
//                (i-tile 32, o-tile 32, LDS transpose; root1 handled here too
//                 as r==8 via separate small range below)
// [17152,17168): root1 transpose (16 blocks: 4096x64 -> wt1 rows 512..575)
// [17168,26384): zero c1 (2359296 ints)
__global__ __launch_bounds__(256) void k_prep(const float4* __restrict__ x,
                                              ushort* __restrict__ xbf,
                                              const int* __restrict__ dstp,
                                              int* __restrict__ deg,
                                              const float* __restrict__ att1,
                                              const float* __restrict__ basis1,
                                              const float* __restrict__ root1,
                                              ushort* __restrict__ wt1,
                                              int* __restrict__ c1i) {
  __shared__ float sT[32 * 33];
  int bid = blockIdx.x, t = threadIdx.x;
  if (bid < 16384) {
    int i = bid * 256 + t;
    float4 v = x[i];
    ushort4 o;
    o.x = f2bf(v.x); o.y = f2bf(v.y); o.z = f2bf(v.z); o.w = f2bf(v.w);
    *(ushort4*)(xbf + (size_t)i * 4) = o;
  } else if (bid < 16896) {
    int e = (bid - 16384) * 256 + t;
    atomicAdd(&deg[dstp[e]], 1);
  } else if (bid < 17152) {
    int bb = bid - 16896;              // 256 blocks: 128 i-tiles x 2 o-tiles
    int i0 = (bb >> 1) * 32, o0 = (bb & 1) * 32;
    int ol = t & 31, ir = t >> 5;      // ir = 0..7
    float a[8][4] = {};
    for (int b = 0; b < 30; ++b) {
      float w0 = att1[0 * 30 + b], w1 = att1[1 * 30 + b], w2 = att1[2 * 30 + b], w3 = att1[3 * 30 + b];
      float w4 = att1[4 * 30 + b], w5 = att1[5 * 30 + b], w6 = att1[6 * 30 + b], w7 = att1[7 * 30 + b];
#pragma unroll
      for (int k = 0; k < 4; ++k) {
        float v = basis1[(size_t)b * 262144 + (size_t)(i0 + ir + k * 8) * 64 + o0 + ol];
        a[0][k] += w0 * v; a[1][k] += w1 * v; a[2][k] += w2 * v; a[3][k] += w3 * v;
        a[4][k] += w4 * v; a[5][k] += w5 * v; a[6][k] += w6 * v; a[7][k] += w7 * v;
      }
    }
    for (int r = 0; r < 8; ++r) {
#pragma unroll
      for (int k = 0; k < 4; ++k) sT[ol * 33 + ir + k * 8] = a[r][k];
      __syncthreads();
#pragma unroll
      for (int k = 0; k < 4; ++k) {
        int orow = ir + k * 8, icol = ol;
        wt1[(size_t)(r * 64 + o0 + orow) * 4096 + i0 + icol] = f2bf(sT[orow * 33 + icol]);
      }
      __syncthreads();
    }
  } else if (bid < 17168) {
    int bb = bid - 17152;              // 16 blocks: root1 4096x64 -> rows 512+o
    int i0 = bb * 256;                 // 256 i per block, via 32x32 subtiles x2... use 8 subtiles of 32i
    int ol = t & 31, ir = t >> 5;
    for (int s = 0; s < 8; ++s) {      // 8 sub-tiles of 32 i
      int ib = i0 + s * 32;
#pragma unroll
      for (int k = 0; k < 4; ++k) {    // o halves: k<2 -> o 0..31 rows? handle 64 o in two halves
        // load root1[(ib+ir+?)..][..]: do two 32x32 transposes (o0=0,32)
      }
      for (int oh = 0; oh < 2; ++oh) {
        int o0 = oh * 32;
#pragma unroll
        for (int k = 0; k < 4; ++k)
          sT[ol * 33 + ir + k * 8] = root1[(size_t)(ib + ir + k * 8) * 64 + o0 + ol];
        __syncthreads();
#pragma unroll
        for (int k = 0; k < 4; ++k) {
          int orow = ir + k * 8, icol = ol;
          wt1[(size_t)(512 + o0 + orow) * 4096 + ib + icol] = f2bf(sT[orow * 33 + icol]);
        }
        __syncthreads();
      }
    }
  } else {
    int flat = (bid - 17168) * 256 + t;  // < 2359296
    c1i[flat] = 0;
  }
}

// ---------------- exclusive scan over 4096 degrees (1 block) --------------
__global__ __launch_bounds__(1024) void k_scan(const int* __restrict__ deg,
                                               int* __restrict__ rowptr,
                                               int* __restrict__ cursor,
                                               float* __restrict__ dinv) {
  __shared__ int part[1024];
  int t = threadIdx.x;
  int base = t * 4;
  int d0 = deg[base], d1 = deg[base + 1], d2 = deg[base + 2], d3 = deg[base + 3];
  int s = d0 + d1 + d2 + d3;
  part[t] = s;
  __syncthreads();
  for (int off = 1; off < 1024; off <<= 1) {
    int v = part[t];
    int u = (t >= off) ? part[t - off] : 0;
    __syncthreads();
    part[t] = v + u;
    __syncthreads();
  }
  int incl = part[t];
  int excl = incl - s;
  int p0 = excl, p1 = excl + d0, p2 = p1 + d1, p3 = p2 + d2;
  rowptr[base] = p0; rowptr[base + 1] = p1; rowptr[base + 2] = p2; rowptr[base + 3] = p3;
  cursor[base] = p0; cursor[base + 1] = p1; cursor[base + 2] = p2; cursor[base + 3] = p3;
  dinv[base]     = 1.0f / fmaxf((float)d0, 1.0f);
  dinv[base + 1] = 1.0f / fmaxf((float)d1, 1.0f);
  dinv[base + 2] = 1.0f / fmaxf((float)d2, 1.0f);
  dinv[base + 3] = 1.0f / fmaxf((float)d3, 1.0f);
  if (t == 1023) rowptr[4096] = incl;
}

// ---------------- fused mid: CSR-fill | W2 combine -------------------------
__global__ __launch_bounds__(256) void k_mid(const int* __restrict__ srcp,
                                             const int* __restrict__ dstp,
                                             const int* __restrict__ et,
                                             int* __restrict__ cursor,
                                             int* __restrict__ spack,
                                             const float* __restrict__ att2,
                                             const float* __restrict__ basis2,
                                             const float* __restrict__ root2,
                                             float* __restrict__ w2e) {
  int bid = blockIdx.x, t = threadIdx.x;
  if (bid < 512) {
    int e = bid * 256 + t;
    int d = dstp[e];
    int pos = atomicAdd(&cursor[d], 1);
    spack[pos] = (srcp[e] << 3) | et[e];
  } else {
    int r = bid - 512;  // 0..8
    for (int q = t; q < 1024; q += 256) {
      float a = 0.f;
      if (r < 8) {
        for (int b = 0; b < 30; ++b) a += att2[r * 30 + b] * basis2[b * 1024 + q];
      } else {
        a = root2[q];
      }
      w2e[r * 1024 + q] = a;
    }
  }
}

// ---------------- split-K GEMM: c1[4096][576] += xbf @ wt1^T --------------
// BM=128 BN=64 BK=64, SPLITK=4 (16 K-steps), 256 thr (2x2 waves, 64x32/wave).
// SINGLE-buffer LDS (24KB -> ~5 blocks/CU), m97-style 2-barrier loop.
// XOR-chunk swizzle both-sides (rule #21). Atomic f32 epilogue.
__global__ __launch_bounds__(256, 5) void k_gemm1(const ushort* __restrict__ xbf,
                                                  const ushort* __restrict__ wt1,
                                                  float* __restrict__ c1) {
  __shared__ __align__(16) ushort As[128 * 64];
  __shared__ __align__(16) ushort Bs[64 * 64];
  int bid = blockIdx.x;
  int swz = (bid & 7) * 144 + (bid >> 3);  // 1152 = 8*144, bijective
  int kp = swz / 288, t2 = swz % 288;
  int bm = t2 / 9, bn = t2 % 9;
  int m0 = bm * 128, n0 = bn * 64, kbase = kp * 1024;
  int tid = threadIdx.x;
  int lane = tid & 63, wid = tid >> 6;
  int wm = wid >> 1, wn = wid & 1;

  f32x4 acc[4][2] = {};

  for (int tt = 0; tt < 16; ++tt) {
    int k0 = kbase + tt * 64;
#pragma unroll
    for (int it = 0; it < 4; ++it) {
      int flat = it * 256 + tid;
      int row = flat >> 3, gg = flat & 7;
      int gcol = k0 + ((gg ^ (row & 7)) << 3);  // pre-swizzled global source
      const ushort* g = xbf + (size_t)(m0 + row) * 4096 + gcol;
      ushort* l = &As[(it * 256 + wid * 64) * 8];  // linear LDS dest
      __builtin_amdgcn_global_load_lds((const __attribute__((address_space(1))) void*)g,
                                       (__attribute__((address_space(3))) void*)l, 16, 0, 0);
    }
#pragma unroll
    for (int it = 0; it < 2; ++it) {
      int flat = it * 256 + tid;
      int row = flat >> 3, gg = flat & 7;
      int gcol = k0 + ((gg ^ (row & 7)) << 3);
      const ushort* g = wt1 + (size_t)(n0 + row) * 4096 + gcol;
      ushort* l = &Bs[(it * 256 + wid * 64) * 8];
      __builtin_amdgcn_global_load_lds((const __attribute__((address_space(1))) void*)g,
                                       (__attribute__((address_space(3))) void*)l, 16, 0, 0);
    }
    __syncthreads();  // compiler drains vmcnt(0) here — loads landed for all waves
    int q = lane >> 4, sw = lane & 7, r16 = lane & 15;
#pragma unroll
    for (int ks = 0; ks < 2; ++ks) {
      int co = ((ks * 4 + q) ^ sw) << 3;
      bf16x8 b0 = *(const bf16x8*)&Bs[(wn * 32 + 0 * 16 + r16) * 64 + co];
      bf16x8 b1 = *(const bf16x8*)&Bs[(wn * 32 + 1 * 16 + r16) * 64 + co];
      bf16x8 a0 = *(const bf16x8*)&As[(wm * 64 + 0 * 16 + r16) * 64 + co];
      bf16x8 a1 = *(const bf16x8*)&As[(wm * 64 + 1 * 16 + r16) * 64 + co];
      bf16x8 a2 = *(const bf16x8*)&As[(wm * 64 + 2 * 16 + r16) * 64 + co];
      bf16x8 a3 = *(const bf16x8*)&As[(wm * 64 + 3 * 16 + r16) * 64 + co];
      __builtin_amdgcn_s_setprio(1);
      acc[0][0] = __builtin_amdgcn_mfma_f32_16x16x32_bf16(a0, b0, acc[0][0], 0, 0, 0);
      acc[0][1] = __builtin_amdgcn_mfma_f32_16x16x32_bf16(a0, b1, acc[0][1], 0, 0, 0);
      acc[1][0] = __builtin_amdgcn_mfma_f32_16x16x32_bf16(a1, b0, acc[1][0], 0, 0, 0);
      acc[1][1] = __builtin_amdgcn_mfma_f32_16x16x32_bf16(a1, b1, acc[1][1], 0, 0, 0);
      acc[2][0] = __builtin_amdgcn_mfma_f32_16x16x32_bf16(a2, b0, acc[2][0], 0, 0, 0);
      acc[2][1] = __builtin_amdgcn_mfma_f32_16x16x32_bf16(a2, b1, acc[2][1], 0, 0, 0);
      acc[3][0] = __builtin_amdgcn_mfma_f32_16x16x32_bf16(a3, b0, acc[3][0], 0, 0, 0);
      acc[3][1] = __builtin_amdgcn_mfma_f32_16x16x32_bf16(a3, b1, acc[3][1], 0, 0, 0);
      __builtin_amdgcn_s_setprio(0);
    }
    __syncthreads();  // LDS free for next stage
  }

  int cf = lane & 15, rf4 = (lane >> 4) * 4;
#pragma unroll
  for (int mi = 0; mi < 4; ++mi)
#pragma unroll
    for (int ni = 0; ni < 2; ++ni) {
      int gcol = n0 + wn * 32 + ni * 16 + cf;
#pragma unroll
      for (int j = 0; j < 4; ++j) {
        int grow = m0 + wm * 64 + mi * 16 + rf4 + j;
        atomicAdd(&c1[(size_t)grow * 576 + gcol], acc[mi][ni][j]);
      }
    }
}

// -------- fused layer-1 aggregate + relu + layer-2 transform (4 nodes/blk) -
__global__ __launch_bounds__(256) void k_agg1h2(const float* __restrict__ c1,
                                                const int* __restrict__ rowptr,
                                                const int* __restrict__ spack,
                                                const float* __restrict__ dinv,
                                                const float* __restrict__ bias1,
                                                const float* __restrict__ w2e,
                                                float* __restrict__ h2c) {
  __shared__ float sh[4][64];
  int g = threadIdx.x >> 6, t = threadIdx.x & 63;
  int n = blockIdx.x * 4 + g;
  int s0 = rowptr[n], s1 = rowptr[n + 1];
  float acc = 0.f;
  int e = s0;
  for (; e + 3 < s1; e += 4) {
    int p0 = spack[e], p1 = spack[e + 1], p2 = spack[e + 2], p3 = spack[e + 3];
    float v0 = c1[(size_t)(p0 >> 3) * 576 + (p0 & 7) * 64 + t];
    float v1 = c1[(size_t)(p1 >> 3) * 576 + (p1 & 7) * 64 + t];
    float v2 = c1[(size_t)(p2 >> 3) * 576 + (p2 & 7) * 64 + t];
    float v3 = c1[(size_t)(p3 >> 3) * 576 + (p3 & 7) * 64 + t];
    acc += (v0 + v1) + (v2 + v3);
  }
  for (; e < s1; ++e) {
    int p = spack[e];
    acc += c1[(size_t)(p >> 3) * 576 + (p & 7) * 64 + t];
  }
  float v = acc * dinv[n] + c1[(size_t)n * 576 + 512 + t] + bias1[t];
  sh[g][t] = fmaxf(v, 0.f);
  __syncthreads();
  float* o = h2c + (size_t)n * 144;
  for (int rc = t; rc < 144; rc += 64) {
    int r9 = rc >> 4, c = rc & 15;
    const float* w = w2e + r9 * 1024 + c;
    float a = 0.f;
#pragma unroll
    for (int hh = 0; hh < 64; ++hh) a += sh[g][hh] * w[hh * 16];
    o[rc] = a;
  }
}

// ---------------- layer-2 aggregate + root + bias + log_softmax -----------
__global__ __launch_bounds__(64) void k_agg2(const float* __restrict__ h2c,
                                             const int* __restrict__ rowptr,
                                             const int* __restrict__ spack,
                                             const float* __restrict__ dinv,
                                             const float* __restrict__ bias2,
                                             float* __restrict__ out) {
  __shared__ float red[64];
  int n = blockIdx.x, t = threadIdx.x;
  int c = t & 15, q = t >> 4;
  int s0 = rowptr[n], s1 = rowptr[n + 1];
  float acc = 0.f;
  for (int e = s0 + q; e < s1; e += 4) {
    int p = spack[e];
    acc += h2c[(size_t)(p >> 3) * 144 + (p & 7) * 16 + c];
  }
  red[t] = acc;
  __syncthreads();
  if (t < 16) {
    float sum = red[c] + red[16 + c] + red[32 + c] + red[48 + c];
    float v = sum * dinv[n] + h2c[(size_t)n * 144 + 128 + c] + bias2[c];
    float m = v;
#pragma unroll
    for (int off = 1; off < 16; off <<= 1) m = fmaxf(m, __shfl_xor(m, off, 64));
    float ex = expf(v - m);
    float s = ex;
#pragma unroll
    for (int off = 1; off < 16; off <<= 1) s += __shfl_xor(s, off, 64);
    out[n * 16 + c] = v - m - logf(s);
  }
}

extern "C" void kernel_launch(void* const* d_in, const int* in_sizes, int n_in,
                              void* d_out, int out_size, void* d_ws, size_t ws_size,
                              hipStream_t stream) {
  const float* x      = (const float*)d_in[0];
  const int*   ei     = (const int*)d_in[1];
  const int*   et     = (const int*)d_in[2];
  const float* basis1 = (const float*)d_in[3];
  const float* att1   = (const float*)d_in[4];
  const float* root1  = (const float*)d_in[5];
  const float* bias1  = (const float*)d_in[6];
  const float* basis2 = (const float*)d_in[7];
  const float* att2   = (const float*)d_in[8];
  const float* root2  = (const float*)d_in[9];
  const float* bias2  = (const float*)d_in[10];
  float* out = (float*)d_out;

  char* ws = (char*)d_ws;
  size_t off = 0;
  auto alloc = [&](size_t bytes) {
    void* p = ws + off;
    off = (off + bytes + 255) & ~(size_t)255;
    return p;
  };
  ushort* xbf  = (ushort*)alloc((size_t)N_CNT * N_CNT * 2);
  ushort* wt1  = (ushort*)alloc((size_t)576 * 4096 * 2);
  float*  c1   = (float*)alloc((size_t)N_CNT * 576 * 4);
  float*  w2e  = (float*)alloc((size_t)9 * 64 * 16 * 4);
  float*  h2c  = (float*)alloc((size_t)N_CNT * 144 * 4);
  int*    deg    = (int*)alloc(4096 * 4);
  float*  dinv   = (float*)alloc(4096 * 4);
  int*    rowptr = (int*)alloc(4097 * 4);
  int*    cursor = (int*)alloc(4096 * 4);
  int*    spack  = (int*)alloc((size_t)E_CNT * 4);

  const int* srcp = ei;
  const int* dstp = ei + E_CNT;

  hipMemsetAsync(deg, 0, 4096 * 4, stream);
  k_prep<<<26384, 256, 0, stream>>>((const float4*)x, xbf, dstp, deg,
                                    att1, basis1, root1, wt1, (int*)c1);
  k_scan<<<1, 1024, 0, stream>>>(deg, rowptr, cursor, dinv);
  k_mid<<<521, 256, 0, stream>>>(srcp, dstp, et, cursor, spack,
                                 att2, basis2, root2, w2e);
  k_gemm1<<<1152, 256, 0, stream>>>(xbf, wt1, c1);
  k_agg1h2<<<1024, 256, 0, stream>>>(c1, rowptr, spack, dinv, bias1, w2e, h2c);
  k_agg2<<<4096, 64, 0, stream>>>(h2c, rowptr, spack, dinv, bias2, out);
}